// Round 2
// baseline (629.784 us; speedup 1.0000x reference)
//
#include <hip/hip_runtime.h>
#include <math.h>

// Problem constants (fixed-shape problem)
#define NN 131072   // nodes
#define G  256      // groups
#define E  384      // embed
#define H  6        // heads
#define DH 64       // head dim
#define OUTD 256    // output dim
#define MAXN 1024   // max segment length

// Workspace layout (float indices)
#define WS_QK   0                       // 6*384 folded q@Wk
#define WS_C    2304                    // 6 folded q@bk
#define WS_OFF  2432                    // 256 int32 segment offsets
#define WS_SC   4096                    // N*6 scores
#define WS_XBAR (4096 + NN*6)           // 256*6*384 attn-weighted feature means

// ---------------------------------------------------------------------------
// K0: segment offsets (scan) + fold query through Wq and Wk.
// qk[h][e] = sum_d qv[h*64+d]*Wk[h*64+d][e],  c[h] = sum_d qv[h*64+d]*bk[h*64+d]
// qv = 0.125*(query@Wq.T + bq)   (1/sqrt(64) pre-scale, as PyTorch MHA)
// ---------------------------------------------------------------------------
__global__ __launch_bounds__(384) void k0_prep(
    const int* __restrict__ sizes, const float* __restrict__ query,
    const float* __restrict__ Wq, const float* __restrict__ bq,
    const float* __restrict__ Wk, const float* __restrict__ bk,
    float* __restrict__ wsf) {
  __shared__ int s_scan[G];
  __shared__ float s_q[E];
  __shared__ float s_qv[E];
  const int tid = threadIdx.x;
  const int lane = tid & 63;
  const int wv = tid >> 6;            // 0..5

  if (tid < G) s_scan[tid] = sizes[tid];
  if (tid < E) s_q[tid] = query[tid];
  __syncthreads();
  // Hillis-Steele inclusive scan over 256 sizes
  for (int d = 1; d < G; d <<= 1) {
    int t = 0;
    if (tid < G && tid >= d) t = s_scan[tid - d];
    __syncthreads();
    if (tid < G) s_scan[tid] += t;
    __syncthreads();
  }
  int* offs = (int*)(wsf + WS_OFF);
  if (tid < G) offs[tid] = s_scan[tid] - sizes[tid];   // exclusive

  // q_vec: wave-per-row (coalesced reads of Wq rows)
  for (int i = wv; i < E; i += 6) {
    const float* wrow = Wq + (size_t)i * E;
    float a = 0.f;
#pragma unroll
    for (int j = 0; j < 6; j++) a += wrow[j * 64 + lane] * s_q[j * 64 + lane];
#pragma unroll
    for (int mm = 1; mm < 64; mm <<= 1) a += __shfl_xor(a, mm, 64);
    if (lane == 0) s_qv[i] = 0.125f * (a + bq[i]);
  }
  __syncthreads();

  // qk: thread t owns column e=t for all 6 heads; loads coalesced across threads
#pragma unroll
  for (int h = 0; h < H; h++) {
    const float* wk = Wk + (size_t)(h * DH) * E + tid;
    float a = 0.f;
#pragma unroll 8
    for (int d = 0; d < DH; d++) a += s_qv[h * DH + d] * wk[(size_t)d * E];
    wsf[WS_QK + h * E + tid] = a;
  }
  if (tid < H) {
    float a = 0.f;
    for (int d = 0; d < DH; d++) a += s_qv[tid * DH + d] * bk[tid * DH + d];
    wsf[WS_C + tid] = a;
  }
}

// ---------------------------------------------------------------------------
// K1: scores[n][h] = x[n]·qk[h] + c[h].  Wave-per-node, qk in registers,
// butterfly reduce. Perfectly balanced flat pass over node_feat (201 MB).
// ---------------------------------------------------------------------------
__global__ __launch_bounds__(256) void k1_scores(
    const float* __restrict__ x, const float* __restrict__ wsf,
    float* __restrict__ scores) {
  const int lane = threadIdx.x & 63;
  const int wid = (blockIdx.x * blockDim.x + threadIdx.x) >> 6;
  const int nwaves = (gridDim.x * blockDim.x) >> 6;

  float qkr[H][6], cr[H];
#pragma unroll
  for (int h = 0; h < H; h++) {
    cr[h] = wsf[WS_C + h];
#pragma unroll
    for (int j = 0; j < 6; j++) qkr[h][j] = wsf[WS_QK + h * E + j * 64 + lane];
  }

  for (int n = wid; n < NN; n += nwaves) {
    const float* xr = x + (size_t)n * E;
    float xv[6];
#pragma unroll
    for (int j = 0; j < 6; j++) xv[j] = xr[j * 64 + lane];
    float p[H];
#pragma unroll
    for (int h = 0; h < H; h++) {
      float a = 0.f;
#pragma unroll
      for (int j = 0; j < 6; j++) a += xv[j] * qkr[h][j];
      p[h] = a;
    }
#pragma unroll
    for (int h = 0; h < H; h++)
#pragma unroll
      for (int mm = 1; mm < 64; mm <<= 1) p[h] += __shfl_xor(p[h], mm, 64);
    if (lane < H) {
      float v = p[0] + cr[0];
#pragma unroll
      for (int h = 1; h < H; h++) v = (lane == h) ? (p[h] + cr[h]) : v;
      scores[(size_t)n * H + lane] = v;
    }
  }
}

// ---------------------------------------------------------------------------
// K2: per (group, e-chunk of 128): softmax over segment (in LDS) then
// xbar[g][h][e] = sum_n attn[n][h] * x[off+n][e].
// 768 blocks x 512 threads; Phase C splits nodes 4-way (np) for load-latency
// hiding (24 waves/CU vs 6 before), partials combined through LDS.
// ---------------------------------------------------------------------------
#define K2T 512
__global__ __launch_bounds__(K2T) void k2_pool(
    const float* __restrict__ x, const int* __restrict__ sizes,
    const float* __restrict__ wsf, float* __restrict__ xbar) {
  __shared__ float pbuf[H][MAXN];      // 24 KB attn weights (unnormalized)
  __shared__ float redm[8][H];
  __shared__ float redl[8][H];
  __shared__ float psum[4][H][128];    // 12 KB per-np partials
  const int tid = threadIdx.x;
  const int w = tid >> 6;              // 0..7
  const int c = blockIdx.x % 3;        // e-chunk
  const int g = blockIdx.x / 3;
  const int* offs = (const int*)(wsf + WS_OFF);
  const int off = offs[g];
  const int Ng = sizes[g];
  const float* sc = wsf + WS_SC + (size_t)off * H;

  // Phase A: stage scores into LDS, per-head running max
  float m[H];
#pragma unroll
  for (int h = 0; h < H; h++) m[h] = -3.0e38f;
  for (int n = tid; n < Ng; n += K2T) {
#pragma unroll
    for (int h = 0; h < H; h++) {
      float s = sc[(size_t)n * H + h];
      pbuf[h][n] = s;
      m[h] = fmaxf(m[h], s);
    }
  }
#pragma unroll
  for (int h = 0; h < H; h++)
#pragma unroll
    for (int mm = 1; mm < 64; mm <<= 1) m[h] = fmaxf(m[h], __shfl_xor(m[h], mm, 64));
  if ((tid & 63) == 0)
#pragma unroll
    for (int h = 0; h < H; h++) redm[w][h] = m[h];
  __syncthreads();
#pragma unroll
  for (int h = 0; h < H; h++) {
    m[h] = redm[0][h];
#pragma unroll
    for (int ww = 1; ww < 8; ww++) m[h] = fmaxf(m[h], redm[ww][h]);
  }

  // Phase B: exp in place, per-head sum; zero-pad to multiple of 32
  float l[H];
#pragma unroll
  for (int h = 0; h < H; h++) l[h] = 0.f;
  for (int n = tid; n < Ng; n += K2T) {
#pragma unroll
    for (int h = 0; h < H; h++) {
      float p = __expf(pbuf[h][n] - m[h]);
      pbuf[h][n] = p;
      l[h] += p;
    }
  }
  const int NgP = (Ng + 31) & ~31;     // <= MAXN since Ng <= MAXN
  for (int n = Ng + tid; n < NgP; n += K2T)
#pragma unroll
    for (int h = 0; h < H; h++) pbuf[h][n] = 0.f;
#pragma unroll
  for (int h = 0; h < H; h++)
#pragma unroll
    for (int mm = 1; mm < 64; mm <<= 1) l[h] += __shfl_xor(l[h], mm, 64);
  if ((tid & 63) == 0)
#pragma unroll
    for (int h = 0; h < H; h++) redl[w][h] = l[h];
  __syncthreads();                     // also orders pbuf writes before Phase C
  float inv[H];
#pragma unroll
  for (int h = 0; h < H; h++) {
    float s = redl[0][h];
#pragma unroll
    for (int ww = 1; ww < 8; ww++) s += redl[ww][h];
    inv[h] = 1.f / s;
  }

  // Phase C: thread owns feature column c*128+col, node-quarter np.
  const int col = tid & 127;
  const int np = tid >> 7;             // 0..3
  const int q4 = NgP >> 2;             // multiple of 8
  const int n0 = np * q4, n1 = n0 + q4;
  float acc[H];
#pragma unroll
  for (int h = 0; h < H; h++) acc[h] = 0.f;
  const float* xcol = x + (size_t)off * E + c * 128 + col;
  for (int n = n0; n < n1; n += 8) {
    float xv[8];
#pragma unroll
    for (int k = 0; k < 8; k++) {
      int nn = n + k;
      nn = nn < Ng ? nn : Ng - 1;      // clamped; pad attn weight is 0
      xv[k] = xcol[(size_t)nn * E];
    }
#pragma unroll
    for (int h = 0; h < H; h++) {
      const float4 p0 = *(const float4*)&pbuf[h][n];      // broadcast reads
      const float4 p1 = *(const float4*)&pbuf[h][n + 4];
      acc[h] += p0.x * xv[0] + p0.y * xv[1] + p0.z * xv[2] + p0.w * xv[3]
              + p1.x * xv[4] + p1.y * xv[5] + p1.z * xv[6] + p1.w * xv[7];
    }
  }
#pragma unroll
  for (int h = 0; h < H; h++) psum[np][h][col] = acc[h];
  __syncthreads();
  if (np == 0) {
#pragma unroll
    for (int h = 0; h < H; h++) {
      float a = psum[0][h][col] + psum[1][h][col] + psum[2][h][col] + psum[3][h][col];
      xbar[((size_t)g * H + h) * E + c * 128 + col] = a * inv[h];
    }
  }
}

// ---------------------------------------------------------------------------
// K3: one block per group. pooled = blockdiag(Wv)·xbar + bv ; om = Wo·pooled
// + bo ; out = Wp·om + bp.  Wave-per-output-row dot: lane-split K (coalesced
// 256B weight wave-loads, L2-hot) + 6-step butterfly. 256 blocks saturate CUs.
// ---------------------------------------------------------------------------
__global__ __launch_bounds__(256) void k3_group(
    const float* __restrict__ xbar,
    const float* __restrict__ Wv, const float* __restrict__ bv,
    const float* __restrict__ Wo, const float* __restrict__ bo,
    const float* __restrict__ Wp, const float* __restrict__ bp,
    float* __restrict__ out) {
  __shared__ float xb[H * E];          // 9.2 KB
  __shared__ float pooled[E];
  __shared__ float om[E];
  __shared__ float ob[OUTD];
  const int tid = threadIdx.x;
  const int lane = tid & 63;
  const int wv = tid >> 6;             // 0..3
  const int g = blockIdx.x;

  for (int i = tid; i < H * E; i += 256) xb[i] = xbar[(size_t)g * (H * E) + i];
  __syncthreads();

  // pooled[i] = Wv[i,:] · xb[h(i)] + bv[i]
  for (int i = wv; i < E; i += 4) {
    const float* wrow = Wv + (size_t)i * E;
    const float* xrow = xb + (i >> 6) * E;
    float a = 0.f;
#pragma unroll
    for (int j = 0; j < 6; j++) a += wrow[j * 64 + lane] * xrow[j * 64 + lane];
#pragma unroll
    for (int mm = 1; mm < 64; mm <<= 1) a += __shfl_xor(a, mm, 64);
    if (lane == 0) pooled[i] = a + bv[i];
  }
  __syncthreads();

  // om[i] = Wo[i,:] · pooled + bo[i]
  for (int i = wv; i < E; i += 4) {
    const float* wrow = Wo + (size_t)i * E;
    float a = 0.f;
#pragma unroll
    for (int j = 0; j < 6; j++) a += wrow[j * 64 + lane] * pooled[j * 64 + lane];
#pragma unroll
    for (int mm = 1; mm < 64; mm <<= 1) a += __shfl_xor(a, mm, 64);
    if (lane == 0) om[i] = a + bo[i];
  }
  __syncthreads();

  // ob[o] = Wp[o,:] · om + bp[o]
  for (int o = wv; o < OUTD; o += 4) {
    const float* wrow = Wp + (size_t)o * E;
    float a = 0.f;
#pragma unroll
    for (int j = 0; j < 6; j++) a += wrow[j * 64 + lane] * om[j * 64 + lane];
#pragma unroll
    for (int mm = 1; mm < 64; mm <<= 1) a += __shfl_xor(a, mm, 64);
    if (lane == 0) ob[o] = a + bp[o];
  }
  __syncthreads();

  for (int i = tid; i < OUTD; i += 256) out[(size_t)g * OUTD + i] = ob[i];
}

// ---------------------------------------------------------------------------
extern "C" void kernel_launch(void* const* d_in, const int* in_sizes, int n_in,
                              void* d_out, int out_size, void* d_ws, size_t ws_size,
                              hipStream_t stream) {
  const float* x     = (const float*)d_in[0];
  const int*   sizes = (const int*)d_in[1];
  const float* query = (const float*)d_in[2];
  const float* Wq    = (const float*)d_in[3];
  const float* bq    = (const float*)d_in[4];
  const float* Wk    = (const float*)d_in[5];
  const float* bk    = (const float*)d_in[6];
  const float* Wv    = (const float*)d_in[7];
  const float* bv    = (const float*)d_in[8];
  const float* Wo    = (const float*)d_in[9];
  const float* bo    = (const float*)d_in[10];
  const float* Wp    = (const float*)d_in[11];
  const float* bp    = (const float*)d_in[12];
  float* wsf = (float*)d_ws;
  float* out = (float*)d_out;

  hipLaunchKernelGGL(k0_prep, dim3(1), dim3(384), 0, stream,
                     sizes, query, Wq, bq, Wk, bk, wsf);
  hipLaunchKernelGGL(k1_scores, dim3(2048), dim3(256), 0, stream,
                     x, wsf, wsf + WS_SC);
  hipLaunchKernelGGL(k2_pool, dim3(768), dim3(K2T), 0, stream,
                     x, sizes, wsf, wsf + WS_XBAR);
  hipLaunchKernelGGL(k3_group, dim3(G), dim3(256), 0, stream,
                     wsf + WS_XBAR, Wv, bv, Wo, bo, Wp, bp, out);
}

// Round 3
// 384.887 us; speedup vs baseline: 1.6363x; 1.6363x over previous
//
#include <hip/hip_runtime.h>
#include <math.h>

// Problem constants (fixed-shape problem)
#define NN 131072   // nodes
#define G  256      // groups
#define E  384      // embed
#define H  6        // heads
#define DH 64       // head dim
#define OUTD 256    // output dim
#define MAXN 1024   // max segment length

// Workspace layout (float indices)
#define WS_QK   0                       // 6*384 folded q@Wk
#define WS_C    2304                    // 6 folded q@bk
#define WS_OFF  2432                    // 256 int32 segment offsets
#define WS_QV   2944                    // 384 projected+scaled query
#define WS_SC   4096                    // N*6 scores
#define WS_XBAR (4096 + NN*6)           // 256*6*384 attn-weighted feature means
#define WS_WVT  (WS_XBAR + G*H*E)       // 384x384 Wv transposed [e][i]
#define WS_WOT  (WS_WVT + E*E)          // 384x384 Wo transposed [e][i]
#define WS_WPT  (WS_WOT + E*E)          // 384x256 Wp transposed [e][o]

// ---------------------------------------------------------------------------
// K0a: block 0: segment-offset scan. blocks 1..96: qv rows (wave-per-row).
// qv = 0.125*(query@Wq.T + bq)
// ---------------------------------------------------------------------------
__global__ __launch_bounds__(256) void k0a_scan_qv(
    const int* __restrict__ sizes, const float* __restrict__ query,
    const float* __restrict__ Wq, const float* __restrict__ bq,
    float* __restrict__ wsf) {
  __shared__ int s_scan[G];
  const int tid = threadIdx.x;
  if (blockIdx.x == 0) {
    s_scan[tid] = sizes[tid];
    __syncthreads();
    for (int d = 1; d < G; d <<= 1) {
      int t = (tid >= d) ? s_scan[tid - d] : 0;
      __syncthreads();
      s_scan[tid] += t;
      __syncthreads();
    }
    int* offs = (int*)(wsf + WS_OFF);
    offs[tid] = s_scan[tid] - sizes[tid];          // exclusive
  } else {
    const int lane = tid & 63;
    const int i = (blockIdx.x - 1) * 4 + (tid >> 6);   // 0..383
    float a = 0.f;
#pragma unroll
    for (int j = 0; j < 6; j++)
      a += Wq[(size_t)i * E + j * 64 + lane] * query[j * 64 + lane];
#pragma unroll
    for (int mm = 1; mm < 64; mm <<= 1) a += __shfl_xor(a, mm, 64);
    if (lane == 0) wsf[WS_QV + i] = 0.125f * (a + bq[i]);
  }
}

// ---------------------------------------------------------------------------
// K0b: qk[h][e] = sum_d qv[h*64+d]*Wk[h*64+d][e].  36 blocks = (h, e-chunk64).
// Thread (e_local, d-quarter): 16-deep partial, LDS combine. Coalesced loads.
// ---------------------------------------------------------------------------
__global__ __launch_bounds__(256) void k0b_qk(
    const float* __restrict__ Wk, const float* __restrict__ bk,
    float* __restrict__ wsf) {
  __shared__ float qv_s[64];
  __shared__ float ps[256];
  const int h = blockIdx.x / 6, ec = blockIdx.x % 6;
  const int tid = threadIdx.x;
  if (tid < 64) qv_s[tid] = wsf[WS_QV + h * 64 + tid];
  __syncthreads();
  const int el = tid & 63, dq = tid >> 6;
  float a = 0.f;
#pragma unroll 4
  for (int d = dq * 16; d < dq * 16 + 16; d++)
    a += qv_s[d] * Wk[(size_t)(h * 64 + d) * E + ec * 64 + el];
  ps[tid] = a;
  __syncthreads();
  if (tid < 64)
    wsf[WS_QK + h * E + ec * 64 + tid] =
        ps[tid] + ps[64 + tid] + ps[128 + tid] + ps[192 + tid];
  if (ec == 0 && tid < 64) {                       // wave 0: c[h]
    float p = qv_s[tid] * bk[h * 64 + tid];
#pragma unroll
    for (int mm = 1; mm < 64; mm <<= 1) p += __shfl_xor(p, mm, 64);
    if (tid == 0) wsf[WS_C + h] = p;
  }
}

// ---------------------------------------------------------------------------
// K0t: transpose Wv, Wo (384x384) and Wp (256x384) into ws, 64x64 LDS tiles.
// 96 blocks. Both global read and write coalesced; LDS padded +1.
// ---------------------------------------------------------------------------
__global__ __launch_bounds__(256) void k0t_transpose(
    const float* __restrict__ Wv, const float* __restrict__ Wo,
    const float* __restrict__ Wp, float* __restrict__ wsf) {
  __shared__ float s[64][65];
  const int b = blockIdx.x;
  const float* src;
  float* dst;
  int R, tr, tc;
  if (b < 36)      { src = Wv; dst = wsf + WS_WVT; R = 384; tr = b / 6;        tc = b % 6; }
  else if (b < 72) { src = Wo; dst = wsf + WS_WOT; R = 384; tr = (b - 36) / 6; tc = (b - 36) % 6; }
  else             { src = Wp; dst = wsf + WS_WPT; R = 256; tr = (b - 72) / 6; tc = (b - 72) % 6; }
  const int r0 = tr * 64, c0 = tc * 64;
#pragma unroll
  for (int k = 0; k < 16; k++) {
    int idx = k * 256 + threadIdx.x;
    int r = idx >> 6, cc = idx & 63;
    s[r][cc] = src[(size_t)(r0 + r) * E + c0 + cc];
  }
  __syncthreads();
#pragma unroll
  for (int k = 0; k < 16; k++) {
    int idx = k * 256 + threadIdx.x;
    int cc = idx >> 6, r = idx & 63;
    dst[(size_t)(c0 + cc) * R + r0 + r] = s[r][cc];
  }
}

// ---------------------------------------------------------------------------
// K1: scores[n][h] = x[n]·qk[h] + c[h].  8 lanes per node: lane sub=lane&7
// owns interleaved 16B chunks of e (coalesced 128B/node row segments), qk
// slices in LDS (292-stride => conflict-free b128 broadcast), reduction is
// 3 shfl_xor steps (vs 6) -> 2.25 bpermute/node instead of 36.
// 1024 blocks x 256 = 4096 waves, 32 nodes/wave, exact fit.
// ---------------------------------------------------------------------------
__global__ __launch_bounds__(256) void k1_scores(
    const float* __restrict__ x, const float* __restrict__ wsf,
    float* __restrict__ scores) {
  __shared__ float qk_l[8 * 292];
  __shared__ float c_s[8];
  const int tid = threadIdx.x;
  // fill qk_l: qk_l[sub][h][j][r] = qk[h][(j*8+sub)*4 + r]
  for (int idx = tid; idx < 2304; idx += 256) {
    int sub = idx / 288, rem = idx % 288;
    int h = rem / 48, r2 = rem % 48, j = r2 >> 2, r = r2 & 3;
    qk_l[sub * 292 + h * 48 + j * 4 + r] =
        wsf[WS_QK + h * E + (j * 8 + sub) * 4 + r];
  }
  if (tid < 8) c_s[tid] = (tid < 6) ? wsf[WS_C + tid] : 0.f;
  __syncthreads();

  const int lane = tid & 63;
  const int sub = lane & 7, nod = lane >> 3;
  const int wid = blockIdx.x * 4 + (tid >> 6);     // 0..4095
  const int n0 = wid * 32;
  const float4* x4 = (const float4*)x;             // row = 96 float4s

  float acc[4][6];
#pragma unroll
  for (int o = 0; o < 4; o++)
#pragma unroll
    for (int h = 0; h < 6; h++) acc[o][h] = 0.f;

#pragma unroll 4
  for (int j = 0; j < 12; j++) {
    float4 qk4[6];
#pragma unroll
    for (int h = 0; h < 6; h++)
      qk4[h] = *(const float4*)&qk_l[sub * 292 + h * 48 + j * 4];
    float4 xv[4];
#pragma unroll
    for (int o = 0; o < 4; o++)
      xv[o] = x4[(size_t)(n0 + o * 8 + nod) * 96 + j * 8 + sub];
#pragma unroll
    for (int o = 0; o < 4; o++)
#pragma unroll
      for (int h = 0; h < 6; h++)
        acc[o][h] += qk4[h].x * xv[o].x + qk4[h].y * xv[o].y
                   + qk4[h].z * xv[o].z + qk4[h].w * xv[o].w;
  }
#pragma unroll
  for (int o = 0; o < 4; o++) {
#pragma unroll
    for (int h = 0; h < 6; h++) {
      acc[o][h] += __shfl_xor(acc[o][h], 1, 64);
      acc[o][h] += __shfl_xor(acc[o][h], 2, 64);
      acc[o][h] += __shfl_xor(acc[o][h], 4, 64);
    }
    float v = acc[o][0];
#pragma unroll
    for (int h = 1; h < 6; h++) v = (sub == h) ? acc[o][h] : v;
    if (sub < 6)
      scores[(size_t)(n0 + o * 8 + nod) * H + sub] = v + c_s[sub];
  }
}

// ---------------------------------------------------------------------------
// K2: per (group, e-chunk of 128): softmax over segment (in LDS) then
// xbar[g][h][e] = sum_n attn[n][h] * x[off+n][e].  768 blocks x 512 threads;
// Phase C splits nodes 4-way for latency hiding, partials via LDS.
// ---------------------------------------------------------------------------
#define K2T 512
__global__ __launch_bounds__(K2T) void k2_pool(
    const float* __restrict__ x, const int* __restrict__ sizes,
    const float* __restrict__ wsf, float* __restrict__ xbar) {
  __shared__ float pbuf[H][MAXN];      // 24 KB attn weights (unnormalized)
  __shared__ float redm[8][H];
  __shared__ float redl[8][H];
  __shared__ float psum[4][H][128];    // 12 KB per-np partials
  const int tid = threadIdx.x;
  const int w = tid >> 6;              // 0..7
  const int c = blockIdx.x % 3;        // e-chunk
  const int g = blockIdx.x / 3;
  const int* offs = (const int*)(wsf + WS_OFF);
  const int off = offs[g];
  const int Ng = sizes[g];
  const float* sc = wsf + WS_SC + (size_t)off * H;

  float m[H];
#pragma unroll
  for (int h = 0; h < H; h++) m[h] = -3.0e38f;
  for (int n = tid; n < Ng; n += K2T) {
#pragma unroll
    for (int h = 0; h < H; h++) {
      float s = sc[(size_t)n * H + h];
      pbuf[h][n] = s;
      m[h] = fmaxf(m[h], s);
    }
  }
#pragma unroll
  for (int h = 0; h < H; h++)
#pragma unroll
    for (int mm = 1; mm < 64; mm <<= 1) m[h] = fmaxf(m[h], __shfl_xor(m[h], mm, 64));
  if ((tid & 63) == 0)
#pragma unroll
    for (int h = 0; h < H; h++) redm[w][h] = m[h];
  __syncthreads();
#pragma unroll
  for (int h = 0; h < H; h++) {
    m[h] = redm[0][h];
#pragma unroll
    for (int ww = 1; ww < 8; ww++) m[h] = fmaxf(m[h], redm[ww][h]);
  }

  float l[H];
#pragma unroll
  for (int h = 0; h < H; h++) l[h] = 0.f;
  for (int n = tid; n < Ng; n += K2T) {
#pragma unroll
    for (int h = 0; h < H; h++) {
      float p = __expf(pbuf[h][n] - m[h]);
      pbuf[h][n] = p;
      l[h] += p;
    }
  }
  const int NgP = (Ng + 31) & ~31;
  for (int n = Ng + tid; n < NgP; n += K2T)
#pragma unroll
    for (int h = 0; h < H; h++) pbuf[h][n] = 0.f;
#pragma unroll
  for (int h = 0; h < H; h++)
#pragma unroll
    for (int mm = 1; mm < 64; mm <<= 1) l[h] += __shfl_xor(l[h], mm, 64);
  if ((tid & 63) == 0)
#pragma unroll
    for (int h = 0; h < H; h++) redl[w][h] = l[h];
  __syncthreads();
  float inv[H];
#pragma unroll
  for (int h = 0; h < H; h++) {
    float s = redl[0][h];
#pragma unroll
    for (int ww = 1; ww < 8; ww++) s += redl[ww][h];
    inv[h] = 1.f / s;
  }

  const int col = tid & 127;
  const int np = tid >> 7;             // 0..3
  const int q4 = NgP >> 2;
  const int n0 = np * q4, n1 = n0 + q4;
  float acc[H];
#pragma unroll
  for (int h = 0; h < H; h++) acc[h] = 0.f;
  const float* xcol = x + (size_t)off * E + c * 128 + col;
  for (int n = n0; n < n1; n += 8) {
    float xv[8];
#pragma unroll
    for (int k = 0; k < 8; k++) {
      int nn = n + k;
      nn = nn < Ng ? nn : Ng - 1;
      xv[k] = xcol[(size_t)nn * E];
    }
#pragma unroll
    for (int h = 0; h < H; h++) {
      const float4 p0 = *(const float4*)&pbuf[h][n];
      const float4 p1 = *(const float4*)&pbuf[h][n + 4];
      acc[h] += p0.x * xv[0] + p0.y * xv[1] + p0.z * xv[2] + p0.w * xv[3]
              + p1.x * xv[4] + p1.y * xv[5] + p1.z * xv[6] + p1.w * xv[7];
    }
  }
#pragma unroll
  for (int h = 0; h < H; h++) psum[np][h][col] = acc[h];
  __syncthreads();
  if (np == 0) {
#pragma unroll
    for (int h = 0; h < H; h++) {
      float a = psum[0][h][col] + psum[1][h][col] + psum[2][h][col] + psum[3][h][col];
      xbar[((size_t)g * H + h) * E + c * 128 + col] = a * inv[h];
    }
  }
}

// ---------------------------------------------------------------------------
// K3: one block (768 thr) per group, thread-per-output chain on TRANSPOSED
// weights (coalesced), K-split across thread halves/thirds, combine via LDS.
// No shuffles, 4 accumulators/thread, all weight reads L2-resident.
// ---------------------------------------------------------------------------
__global__ __launch_bounds__(768) void k3_group(
    const float* __restrict__ xbar, const float* __restrict__ wvt,
    const float* __restrict__ wot, const float* __restrict__ wpt,
    const float* __restrict__ bv, const float* __restrict__ bo,
    const float* __restrict__ bp, float* __restrict__ out) {
  __shared__ float xb[H * E];          // 9.2 KB
  __shared__ float pooled[E];
  __shared__ float om[E];
  __shared__ float ps[768];
  const int tid = threadIdx.x;
  const int g = blockIdx.x;

  for (int i = tid; i < H * E; i += 768) xb[i] = xbar[(size_t)g * (H * E) + i];
  __syncthreads();

  {  // stage 1: pooled[i] = Wv[i,:]·xb[head(i),:] + bv
    const int i = tid % 384, ks = tid / 384;
    const float* xh = xb + (i >> 6) * E + ks * 192;
    const float* wp_ = wvt + (size_t)(ks * 192) * E + i;
    float a0 = 0.f, a1 = 0.f, a2 = 0.f, a3 = 0.f;
#pragma unroll 4
    for (int e = 0; e < 192; e += 4) {
      a0 += wp_[(size_t)(e + 0) * E] * xh[e + 0];
      a1 += wp_[(size_t)(e + 1) * E] * xh[e + 1];
      a2 += wp_[(size_t)(e + 2) * E] * xh[e + 2];
      a3 += wp_[(size_t)(e + 3) * E] * xh[e + 3];
    }
    ps[tid] = (a0 + a1) + (a2 + a3);
  }
  __syncthreads();
  if (tid < 384) pooled[tid] = ps[tid] + ps[384 + tid] + bv[tid];
  __syncthreads();

  {  // stage 2: om[i] = Wo[i,:]·pooled + bo
    const int i = tid % 384, ks = tid / 384;
    const float* xh = pooled + ks * 192;
    const float* wp_ = wot + (size_t)(ks * 192) * E + i;
    float a0 = 0.f, a1 = 0.f, a2 = 0.f, a3 = 0.f;
#pragma unroll 4
    for (int e = 0; e < 192; e += 4) {
      a0 += wp_[(size_t)(e + 0) * E] * xh[e + 0];
      a1 += wp_[(size_t)(e + 1) * E] * xh[e + 1];
      a2 += wp_[(size_t)(e + 2) * E] * xh[e + 2];
      a3 += wp_[(size_t)(e + 3) * E] * xh[e + 3];
    }
    ps[tid] = (a0 + a1) + (a2 + a3);
  }
  __syncthreads();
  if (tid < 384) om[tid] = ps[tid] + ps[384 + tid] + bo[tid];
  __syncthreads();

  {  // stage 3: out[o] = Wp[o,:]·om + bp   (3-way K-split of 384)
    const int o = tid % 256, ks = tid / 256;
    const float* xh = om + ks * 128;
    const float* wp_ = wpt + (size_t)(ks * 128) * OUTD + o;
    float a0 = 0.f, a1 = 0.f, a2 = 0.f, a3 = 0.f;
#pragma unroll 4
    for (int e = 0; e < 128; e += 4) {
      a0 += wp_[(size_t)(e + 0) * OUTD] * xh[e + 0];
      a1 += wp_[(size_t)(e + 1) * OUTD] * xh[e + 1];
      a2 += wp_[(size_t)(e + 2) * OUTD] * xh[e + 2];
      a3 += wp_[(size_t)(e + 3) * OUTD] * xh[e + 3];
    }
    ps[tid] = (a0 + a1) + (a2 + a3);
  }
  __syncthreads();
  if (tid < 256)
    out[(size_t)g * OUTD + tid] = ps[tid] + ps[256 + tid] + ps[512 + tid] + bp[tid];
}

// ---------------------------------------------------------------------------
extern "C" void kernel_launch(void* const* d_in, const int* in_sizes, int n_in,
                              void* d_out, int out_size, void* d_ws, size_t ws_size,
                              hipStream_t stream) {
  const float* x     = (const float*)d_in[0];
  const int*   sizes = (const int*)d_in[1];
  const float* query = (const float*)d_in[2];
  const float* Wq    = (const float*)d_in[3];
  const float* bq    = (const float*)d_in[4];
  const float* Wk    = (const float*)d_in[5];
  const float* bk    = (const float*)d_in[6];
  const float* Wv    = (const float*)d_in[7];
  const float* bv    = (const float*)d_in[8];
  const float* Wo    = (const float*)d_in[9];
  const float* bo    = (const float*)d_in[10];
  const float* Wp    = (const float*)d_in[11];
  const float* bp    = (const float*)d_in[12];
  float* wsf = (float*)d_ws;
  float* out = (float*)d_out;

  hipLaunchKernelGGL(k0a_scan_qv, dim3(97), dim3(256), 0, stream,
                     sizes, query, Wq, bq, wsf);
  hipLaunchKernelGGL(k0b_qk, dim3(36), dim3(256), 0, stream, Wk, bk, wsf);
  hipLaunchKernelGGL(k0t_transpose, dim3(96), dim3(256), 0, stream,
                     Wv, Wo, Wp, wsf);
  hipLaunchKernelGGL(k1_scores, dim3(1024), dim3(256), 0, stream,
                     x, wsf, wsf + WS_SC);
  hipLaunchKernelGGL(k2_pool, dim3(768), dim3(K2T), 0, stream,
                     x, sizes, wsf, wsf + WS_XBAR);
  hipLaunchKernelGGL(k3_group, dim3(G), dim3(768), 0, stream,
                     wsf + WS_XBAR, wsf + WS_WVT, wsf + WS_WOT, wsf + WS_WPT,
                     bv, bo, bp, out);
}

// Round 4
// 373.192 us; speedup vs baseline: 1.6876x; 1.0313x over previous
//
#include <hip/hip_runtime.h>
#include <math.h>

// Problem constants (fixed-shape problem)
#define NN 131072   // nodes
#define G  256      // groups
#define E  384      // embed
#define H  6        // heads
#define DH 64       // head dim
#define OUTD 256    // output dim
#define MAXN 1024   // max segment length

#define CHK 256     // nodes per fused-pool chunk
#define SLOTS 4     // max chunks per group (ceil(MAXN/CHK))
#define PART_STRIDE 2316   // 6*384 acc + 6 m + 6 l

// Workspace layout (float indices)
#define WS_QK   0                       // 6*384 folded q@Wk
#define WS_C    2304                    // 6 folded q@bk
#define WS_OFF  2432                    // 256 int32 segment offsets
#define WS_QV   2944                    // 384 projected+scaled query
#define WS_PART 4096                    // 1024 slots x 2316 partials
#define WS_WVT  (WS_PART + G*SLOTS*PART_STRIDE)  // 384x384 Wv^T [e][i]
#define WS_WOT  (WS_WVT + E*E)          // 384x384 Wo^T [e][i]
#define WS_WPT  (WS_WOT + E*E)          // 384x256 Wp^T [e][o]

// ---------------------------------------------------------------------------
// K0a: block 0: segment-offset scan. blocks 1..96: qv rows (wave-per-row).
// qv = 0.125*(query@Wq.T + bq)
// ---------------------------------------------------------------------------
__global__ __launch_bounds__(256) void k0a_scan_qv(
    const int* __restrict__ sizes, const float* __restrict__ query,
    const float* __restrict__ Wq, const float* __restrict__ bq,
    float* __restrict__ wsf) {
  __shared__ int s_scan[G];
  const int tid = threadIdx.x;
  if (blockIdx.x == 0) {
    s_scan[tid] = sizes[tid];
    __syncthreads();
    for (int d = 1; d < G; d <<= 1) {
      int t = (tid >= d) ? s_scan[tid - d] : 0;
      __syncthreads();
      s_scan[tid] += t;
      __syncthreads();
    }
    int* offs = (int*)(wsf + WS_OFF);
    offs[tid] = s_scan[tid] - sizes[tid];          // exclusive
  } else {
    const int lane = tid & 63;
    const int i = (blockIdx.x - 1) * 4 + (tid >> 6);   // 0..383
    float a = 0.f;
#pragma unroll
    for (int j = 0; j < 6; j++)
      a += Wq[(size_t)i * E + j * 64 + lane] * query[j * 64 + lane];
#pragma unroll
    for (int mm = 1; mm < 64; mm <<= 1) a += __shfl_xor(a, mm, 64);
    if (lane == 0) wsf[WS_QV + i] = 0.125f * (a + bq[i]);
  }
}

// ---------------------------------------------------------------------------
// K0b: qk[h][e] = sum_d qv[h*64+d]*Wk[h*64+d][e].  36 blocks = (h, e-chunk64).
// ---------------------------------------------------------------------------
__global__ __launch_bounds__(256) void k0b_qk(
    const float* __restrict__ Wk, const float* __restrict__ bk,
    float* __restrict__ wsf) {
  __shared__ float qv_s[64];
  __shared__ float ps[256];
  const int h = blockIdx.x / 6, ec = blockIdx.x % 6;
  const int tid = threadIdx.x;
  if (tid < 64) qv_s[tid] = wsf[WS_QV + h * 64 + tid];
  __syncthreads();
  const int el = tid & 63, dq = tid >> 6;
  float a = 0.f;
#pragma unroll 4
  for (int d = dq * 16; d < dq * 16 + 16; d++)
    a += qv_s[d] * Wk[(size_t)(h * 64 + d) * E + ec * 64 + el];
  ps[tid] = a;
  __syncthreads();
  if (tid < 64)
    wsf[WS_QK + h * E + ec * 64 + tid] =
        ps[tid] + ps[64 + tid] + ps[128 + tid] + ps[192 + tid];
  if (ec == 0 && tid < 64) {                       // wave 0: c[h]
    float p = qv_s[tid] * bk[h * 64 + tid];
#pragma unroll
    for (int mm = 1; mm < 64; mm <<= 1) p += __shfl_xor(p, mm, 64);
    if (tid == 0) wsf[WS_C + h] = p;
  }
}

// ---------------------------------------------------------------------------
// K0t: transpose Wv, Wo (384x384) and Wp (256x384) into ws, 64x64 LDS tiles.
// ---------------------------------------------------------------------------
__global__ __launch_bounds__(256) void k0t_transpose(
    const float* __restrict__ Wv, const float* __restrict__ Wo,
    const float* __restrict__ Wp, float* __restrict__ wsf) {
  __shared__ float s[64][65];
  const int b = blockIdx.x;
  const float* src;
  float* dst;
  int R, tr, tc;
  if (b < 36)      { src = Wv; dst = wsf + WS_WVT; R = 384; tr = b / 6;        tc = b % 6; }
  else if (b < 72) { src = Wo; dst = wsf + WS_WOT; R = 384; tr = (b - 36) / 6; tc = (b - 36) % 6; }
  else             { src = Wp; dst = wsf + WS_WPT; R = 256; tr = (b - 72) / 6; tc = (b - 72) % 6; }
  const int r0 = tr * 64, c0 = tc * 64;
#pragma unroll
  for (int k = 0; k < 16; k++) {
    int idx = k * 256 + threadIdx.x;
    int r = idx >> 6, cc = idx & 63;
    s[r][cc] = src[(size_t)(r0 + r) * E + c0 + cc];
  }
  __syncthreads();
#pragma unroll
  for (int k = 0; k < 16; k++) {
    int idx = k * 256 + threadIdx.x;
    int cc = idx >> 6, r = idx & 63;
    dst[(size_t)(c0 + cc) * R + r0 + r] = s[r][cc];
  }
}

// ---------------------------------------------------------------------------
// K12: fused scores + chunk-local softmax + weighted pooling, ONE HBM pass
// over x.  Block = (group g, chunk s of 256 nodes); 1024 blocks x 512 thr
// (~760 alive).  Phase 1: k1-style 8-lane scores from HBM -> LDS pbuf.
// Softmax: wave w owns head w (in-wave max/exp/sum, no barriers).
// Phase 2: re-read chunk rows column-wise (L2-hot) accumulating
// acc[h][e] = sum_n p[h][n]*x[n][e]; write partial (acc, m, l) to ws.
// ---------------------------------------------------------------------------
#define PB 264      // pbuf stride: 16B-aligned, bank-spread
__global__ __launch_bounds__(512) void k12_fused(
    const float* __restrict__ x, const int* __restrict__ sizes,
    float* __restrict__ wsf) {
  __shared__ float qk_l[8 * 292];
  __shared__ float c_s[8];
  __shared__ float pbuf[H * PB];
  __shared__ float psum[4][H][128];
  const int g = blockIdx.x & 255, s = blockIdx.x >> 8;
  const int Ng = sizes[g];
  const int rem = Ng - s * CHK;
  if (rem <= 0) return;                            // dead slot, uniform exit
  const int clen = rem < CHK ? rem : CHK;
  const int n0 = ((const int*)(wsf + WS_OFF))[g] + s * CHK;
  const int tid = threadIdx.x;

  for (int idx = tid; idx < 2304; idx += 512) {    // qk: k1 layout
    int sub = idx / 288, r3 = idx % 288;
    int h = r3 / 48, r2 = r3 % 48, j = r2 >> 2, r = r2 & 3;
    qk_l[sub * 292 + h * 48 + j * 4 + r] =
        wsf[WS_QK + h * E + (j * 8 + sub) * 4 + r];
  }
  if (tid < 8) c_s[tid] = (tid < 6) ? wsf[WS_C + tid] : 0.f;
  __syncthreads();

  const int lane = tid & 63, w = tid >> 6;         // 8 waves
  const int sub = lane & 7, nod = lane >> 3;
  const float4* x4 = (const float4*)x;
  {  // phase 1: 32 nodes per wave
    const int base = w * 32;
    float acc[4][6];
#pragma unroll
    for (int o = 0; o < 4; o++)
#pragma unroll
      for (int h = 0; h < 6; h++) acc[o][h] = 0.f;
#pragma unroll 4
    for (int j = 0; j < 12; j++) {
      float4 qk4[6];
#pragma unroll
      for (int h = 0; h < 6; h++)
        qk4[h] = *(const float4*)&qk_l[sub * 292 + h * 48 + j * 4];
      float4 xv[4];
#pragma unroll
      for (int o = 0; o < 4; o++) {
        int nn = base + o * 8 + nod;
        nn = nn < clen ? nn : clen - 1;
        xv[o] = x4[(size_t)(n0 + nn) * 96 + j * 8 + sub];
      }
#pragma unroll
      for (int o = 0; o < 4; o++)
#pragma unroll
        for (int h = 0; h < 6; h++)
          acc[o][h] += qk4[h].x * xv[o].x + qk4[h].y * xv[o].y
                     + qk4[h].z * xv[o].z + qk4[h].w * xv[o].w;
    }
#pragma unroll
    for (int o = 0; o < 4; o++) {
#pragma unroll
      for (int h = 0; h < 6; h++) {
        acc[o][h] += __shfl_xor(acc[o][h], 1, 64);
        acc[o][h] += __shfl_xor(acc[o][h], 2, 64);
        acc[o][h] += __shfl_xor(acc[o][h], 4, 64);
      }
      float v = acc[o][0];
#pragma unroll
      for (int h = 1; h < 6; h++) v = (sub == h) ? acc[o][h] : v;
      if (sub < 6) {
        int nn = base + o * 8 + nod;
        pbuf[sub * PB + nn] = (nn < clen) ? v + c_s[sub] : -1.0e30f;
      }
    }
  }
  __syncthreads();

  float* pslot = wsf + WS_PART + (size_t)(g * SLOTS + s) * PART_STRIDE;
  if (w < 6) {  // softmax stats for head w, in-wave
    float vals[4];
#pragma unroll
    for (int k = 0; k < 4; k++) vals[k] = pbuf[w * PB + lane + k * 64];
    float m = fmaxf(fmaxf(vals[0], vals[1]), fmaxf(vals[2], vals[3]));
#pragma unroll
    for (int mm = 1; mm < 64; mm <<= 1) m = fmaxf(m, __shfl_xor(m, mm, 64));
    float lsum = 0.f;
#pragma unroll
    for (int k = 0; k < 4; k++) {
      float e = __expf(vals[k] - m);
      pbuf[w * PB + lane + k * 64] = e;
      lsum += e;
    }
#pragma unroll
    for (int mm = 1; mm < 64; mm <<= 1) lsum += __shfl_xor(lsum, mm, 64);
    if (lane == 0) { pslot[2304 + w] = m; pslot[2310 + w] = lsum; }
  }
  __syncthreads();

  // phase 2: (col128, node-quarter) x 3 e-chunks; rows are L2-hot
  const int col = tid & 127, np = tid >> 7;
  for (int c = 0; c < 3; c++) {
    float acc[6];
#pragma unroll
    for (int h = 0; h < 6; h++) acc[h] = 0.f;
    const float* xcol = x + (size_t)n0 * E + c * 128 + col;
    for (int n = np * 64; n < np * 64 + 64; n += 8) {
      float xv[8];
#pragma unroll
      for (int k = 0; k < 8; k++) {
        int nn = n + k;
        nn = nn < clen ? nn : clen - 1;              // pad weight is 0
        xv[k] = xcol[(size_t)nn * E];
      }
#pragma unroll
      for (int h = 0; h < 6; h++) {
        const float4 p0 = *(const float4*)&pbuf[h * PB + n];
        const float4 p1 = *(const float4*)&pbuf[h * PB + n + 4];
        acc[h] += p0.x * xv[0] + p0.y * xv[1] + p0.z * xv[2] + p0.w * xv[3]
                + p1.x * xv[4] + p1.y * xv[5] + p1.z * xv[6] + p1.w * xv[7];
      }
    }
#pragma unroll
    for (int h = 0; h < 6; h++) psum[np][h][col] = acc[h];
    __syncthreads();
    if (np == 0)
#pragma unroll
      for (int h = 0; h < 6; h++)
        pslot[h * E + c * 128 + col] =
            psum[0][h][col] + psum[1][h][col] + psum[2][h][col] + psum[3][h][col];
    __syncthreads();
  }
}

// ---------------------------------------------------------------------------
// K3: one block (768 thr) per group.  Prologue: flash-combine <=4 chunk
// partials (acc,m,l) -> xb.  Then thread-per-output chain on transposed
// weights (coalesced, L2-resident), K-split, combine via LDS.
// ---------------------------------------------------------------------------
__global__ __launch_bounds__(768) void k3_group(
    const float* __restrict__ wsf, const int* __restrict__ sizes,
    const float* __restrict__ bv, const float* __restrict__ bo,
    const float* __restrict__ bp, float* __restrict__ out) {
  __shared__ float xb[H * E];          // 9.2 KB
  __shared__ float pooled[E];
  __shared__ float om[E];
  __shared__ float ps[768];
  __shared__ float wgt[SLOTS][H];
  __shared__ float linv[H];
  const int tid = threadIdx.x;
  const int g = blockIdx.x;
  const int nch = (sizes[g] + CHK - 1) / CHK;      // 1..4
  const float* pg = wsf + WS_PART + (size_t)g * SLOTS * PART_STRIDE;
  const float* wvt = wsf + WS_WVT;
  const float* wot = wsf + WS_WOT;
  const float* wpt = wsf + WS_WPT;

  if (tid < H) {
    float m = -3.0e38f;
    for (int s = 0; s < nch; s++)
      m = fmaxf(m, pg[(size_t)s * PART_STRIDE + 2304 + tid]);
    float L = 0.f;
    for (int s = 0; s < nch; s++) {
      float wv_ = __expf(pg[(size_t)s * PART_STRIDE + 2304 + tid] - m);
      wgt[s][tid] = wv_;
      L += pg[(size_t)s * PART_STRIDE + 2310 + tid] * wv_;
    }
    linv[tid] = 1.f / L;
  }
  __syncthreads();
  for (int idx = tid; idx < H * E; idx += 768) {
    int h = idx / E;
    float a = 0.f;
    for (int s = 0; s < nch; s++) a += pg[(size_t)s * PART_STRIDE + idx] * wgt[s][h];
    xb[idx] = a * linv[h];
  }
  __syncthreads();

  {  // stage 1: pooled[i] = Wv[i,:]·xb[head(i),:] + bv
    const int i = tid % 384, ks = tid / 384;
    const float* xh = xb + (i >> 6) * E + ks * 192;
    const float* wp_ = wvt + (size_t)(ks * 192) * E + i;
    float a0 = 0.f, a1 = 0.f, a2 = 0.f, a3 = 0.f;
#pragma unroll 4
    for (int e = 0; e < 192; e += 4) {
      a0 += wp_[(size_t)(e + 0) * E] * xh[e + 0];
      a1 += wp_[(size_t)(e + 1) * E] * xh[e + 1];
      a2 += wp_[(size_t)(e + 2) * E] * xh[e + 2];
      a3 += wp_[(size_t)(e + 3) * E] * xh[e + 3];
    }
    ps[tid] = (a0 + a1) + (a2 + a3);
  }
  __syncthreads();
  if (tid < 384) pooled[tid] = ps[tid] + ps[384 + tid] + bv[tid];
  __syncthreads();

  {  // stage 2: om[i] = Wo[i,:]·pooled + bo
    const int i = tid % 384, ks = tid / 384;
    const float* xh = pooled + ks * 192;
    const float* wp_ = wot + (size_t)(ks * 192) * E + i;
    float a0 = 0.f, a1 = 0.f, a2 = 0.f, a3 = 0.f;
#pragma unroll 4
    for (int e = 0; e < 192; e += 4) {
      a0 += wp_[(size_t)(e + 0) * E] * xh[e + 0];
      a1 += wp_[(size_t)(e + 1) * E] * xh[e + 1];
      a2 += wp_[(size_t)(e + 2) * E] * xh[e + 2];
      a3 += wp_[(size_t)(e + 3) * E] * xh[e + 3];
    }
    ps[tid] = (a0 + a1) + (a2 + a3);
  }
  __syncthreads();
  if (tid < 384) om[tid] = ps[tid] + ps[384 + tid] + bo[tid];
  __syncthreads();

  {  // stage 3: out[o] = Wp[o,:]·om + bp   (3-way K-split of 384)
    const int o = tid % 256, ks = tid / 256;
    const float* xh = om + ks * 128;
    const float* wp_ = wpt + (size_t)(ks * 128) * OUTD + o;
    float a0 = 0.f, a1 = 0.f, a2 = 0.f, a3 = 0.f;
#pragma unroll 4
    for (int e = 0; e < 128; e += 4) {
      a0 += wp_[(size_t)(e + 0) * OUTD] * xh[e + 0];
      a1 += wp_[(size_t)(e + 1) * OUTD] * xh[e + 1];
      a2 += wp_[(size_t)(e + 2) * OUTD] * xh[e + 2];
      a3 += wp_[(size_t)(e + 3) * OUTD] * xh[e + 3];
    }
    ps[tid] = (a0 + a1) + (a2 + a3);
  }
  __syncthreads();
  if (tid < 256)
    out[(size_t)g * OUTD + tid] = ps[tid] + ps[256 + tid] + ps[512 + tid] + bp[tid];
}

// ---------------------------------------------------------------------------
extern "C" void kernel_launch(void* const* d_in, const int* in_sizes, int n_in,
                              void* d_out, int out_size, void* d_ws, size_t ws_size,
                              hipStream_t stream) {
  const float* x     = (const float*)d_in[0];
  const int*   sizes = (const int*)d_in[1];
  const float* query = (const float*)d_in[2];
  const float* Wq    = (const float*)d_in[3];
  const float* bq    = (const float*)d_in[4];
  const float* Wk    = (const float*)d_in[5];
  const float* bk    = (const float*)d_in[6];
  const float* Wv    = (const float*)d_in[7];
  const float* bv    = (const float*)d_in[8];
  const float* Wo    = (const float*)d_in[9];
  const float* bo    = (const float*)d_in[10];
  const float* Wp    = (const float*)d_in[11];
  const float* bp    = (const float*)d_in[12];
  float* wsf = (float*)d_ws;
  float* out = (float*)d_out;

  hipLaunchKernelGGL(k0a_scan_qv, dim3(97), dim3(256), 0, stream,
                     sizes, query, Wq, bq, wsf);
  hipLaunchKernelGGL(k0b_qk, dim3(36), dim3(256), 0, stream, Wk, bk, wsf);
  hipLaunchKernelGGL(k0t_transpose, dim3(96), dim3(256), 0, stream,
                     Wv, Wo, Wp, wsf);
  hipLaunchKernelGGL(k12_fused, dim3(G * SLOTS), dim3(512), 0, stream,
                     x, sizes, wsf);
  hipLaunchKernelGGL(k3_group, dim3(G), dim3(768), 0, stream,
                     wsf, sizes, bv, bo, bp, out);
}